// Round 9
// baseline (488.851 us; speedup 1.0000x reference)
//
#include <hip/hip_runtime.h>
#include <math.h>

// ---------------------------------------------------------------------------
// GCN forward, CSR + 16-wide aggregation for BOTH layers.
// Algebra #1: norm = dinv[r]*dinv[c] => pre-scale features by dinv[c],
//   post-scale row sums by dinv[r].
// Algebra #2: W2 is linear => aggregate the 16-wide u = relu(.)*dinv and
//   apply W2 AFTER aggregation (64B/edge gather over a 6.4MB table).
// CSR build (hierarchical; R3/R4 lesson: no large random atomic targets):
//   k_bhist -> k_bscan -> k_bscatter -> k_bsort2, packed 32-bit pairs.
// GEMM1 R8 lesson: per-lane 16B/iter row streaming needs each 128B line to
//   survive 8 iterations in cache; at 12 waves/CU the live-line set (~6MB)
//   overflowed the 4MB per-XCD L2 -> 3.1x HBM re-fetch (FETCH 638MB).
//   R9 fix: consume the full 128B line IN one unrolled group (8 xfloat4
//   batch loads per row-stream into registers), so line lifetime ~ 0 and
//   FETCH = logical at any occupancy. Grid stays (196,4)=784 blocks.
// ---------------------------------------------------------------------------

#define BSHIFT 7          // 128 rows per bucket
#define CHUNK_E 8192      // edges per bucketing block
#define PACK_SHIFT 25
#define PACK_MASK 0x01FFFFFF

__global__ void k_detect(const int* __restrict__ ei32, int* __restrict__ flag) {
    int t = threadIdx.x;
    bool z = (ei32[2 * t + 1] == 0);
    unsigned long long m = __ballot(z);
    if (t == 0) *flag = (m == 0xFFFFFFFFFFFFFFFFULL) ? 1 : 0;
}

__global__ void k_zero(int* __restrict__ p, int n) {
    int i = blockIdx.x * blockDim.x + threadIdx.x;
    if (i < n) p[i] = 0;
}

// ---------------------------------------------------------------------------
// Pass A: per-block LDS histogram of row-buckets; <=nbuck global atomics/block.
// ---------------------------------------------------------------------------
__global__ __launch_bounds__(256) void k_bhist(
        const void* __restrict__ ei, const int* __restrict__ flag,
        int* __restrict__ bcnt, int E, int nbuck) {
    __shared__ int cnt[1024];
    int tid = threadIdx.x;
    for (int i = tid; i < nbuck; i += 256) cnt[i] = 0;
    __syncthreads();
    int e0 = blockIdx.x * CHUNK_E;
    int e1 = min(E, e0 + CHUNK_E);
    bool f = (*flag) != 0;
    for (int e = e0 + tid; e < e1; e += 256) {
        int r = f ? (int)((const long long*)ei)[e] : ((const int*)ei)[e];
        atomicAdd(&cnt[r >> BSHIFT], 1);
    }
    __syncthreads();
    for (int i = tid; i < nbuck; i += 256)
        if (cnt[i]) atomicAdd(&bcnt[i], cnt[i]);
}

// ---------------------------------------------------------------------------
// Scan bucket counts -> bbase (exclusive), bcur (working copy).
// ---------------------------------------------------------------------------
__global__ __launch_bounds__(1024) void k_bscan(
        const int* __restrict__ bcnt, int* __restrict__ bbase,
        int* __restrict__ bcur, int nbuck, int E,
        int* __restrict__ row_ptr, int n) {
    __shared__ int ls[1024];
    int t = threadIdx.x;
    int v = (t < nbuck) ? bcnt[t] : 0;
    ls[t] = v; __syncthreads();
    for (int off = 1; off < 1024; off <<= 1) {
        int tmp = (t >= off) ? ls[t - off] : 0;
        __syncthreads();
        ls[t] += tmp;
        __syncthreads();
    }
    int ex = ls[t] - v;  // exclusive
    if (t < nbuck) { bbase[t] = ex; bcur[t] = ex; }
    if (t == 0) { bbase[nbuck] = E; row_ptr[n] = E; }
}

// ---------------------------------------------------------------------------
// Pass B: bucket edges into contiguous per-bucket segments (packed 32-bit).
// ---------------------------------------------------------------------------
__global__ __launch_bounds__(256) void k_bscatter(
        const void* __restrict__ ei, const int* __restrict__ flag,
        int* __restrict__ bcur, unsigned int* __restrict__ pair, int E, int nbuck) {
    __shared__ int cnt[1024];
    __shared__ int runs[1024];
    int tid = threadIdx.x;
    for (int i = tid; i < nbuck; i += 256) cnt[i] = 0;
    __syncthreads();
    int e0 = blockIdx.x * CHUNK_E;
    int e1 = min(E, e0 + CHUNK_E);
    bool f = (*flag) != 0;
    for (int e = e0 + tid; e < e1; e += 256) {
        int r = f ? (int)((const long long*)ei)[e] : ((const int*)ei)[e];
        atomicAdd(&cnt[r >> BSHIFT], 1);
    }
    __syncthreads();
    for (int i = tid; i < nbuck; i += 256) {
        int c = cnt[i];
        runs[i] = (c > 0) ? atomicAdd(&bcur[i], c) : 0;
        cnt[i] = 0;  // reuse as local cursor
    }
    __syncthreads();
    for (int e = e0 + tid; e < e1; e += 256) {
        int r, c;
        if (f) { const long long* p = (const long long*)ei; r = (int)p[e]; c = (int)p[E + e]; }
        else   { const int* p = (const int*)ei;             r = p[e];      c = p[E + e]; }
        int b = r >> BSHIFT;
        int pos = runs[b] + atomicAdd(&cnt[b], 1);
        pair[pos] = ((unsigned int)(r & 127) << PACK_SHIFT) | (unsigned int)c;
    }
}

// ---------------------------------------------------------------------------
// Pass C: one block per bucket. LDS histogram -> local exclusive scan ->
// row_ptr + dinv (fused rsqrt), then LDS-cursor scatter to csr_col.
// ---------------------------------------------------------------------------
__global__ __launch_bounds__(256) void k_bsort2(
        const unsigned int* __restrict__ pair, const int* __restrict__ bbase,
        int* __restrict__ row_ptr, float* __restrict__ dinv,
        int* __restrict__ csr_col, int n) {
    __shared__ int cnt[128];
    __shared__ int scn[128];
    __shared__ int cur[128];
    int b = blockIdx.x;
    int lo = b << BSHIFT, hi = min(n, lo + 128);
    int nr = hi - lo;
    int tid = threadIdx.x;
    if (tid < 128) cnt[tid] = 0;
    __syncthreads();
    int s = bbase[b], e = bbase[b + 1];
    for (int j = s + tid; j < e; j += 256)
        atomicAdd(&cnt[pair[j] >> PACK_SHIFT], 1);
    __syncthreads();
    if (tid < 128) scn[tid] = cnt[tid];
    __syncthreads();
    for (int off = 1; off < 128; off <<= 1) {
        int tval = (tid < 128 && tid >= off) ? scn[tid - off] : 0;
        __syncthreads();
        if (tid < 128) scn[tid] += tval;
        __syncthreads();
    }
    if (tid < 128) {
        int rp = s + scn[tid] - cnt[tid];  // exclusive
        cur[tid] = rp;
        if (tid < nr) {
            row_ptr[lo + tid] = rp;
            dinv[lo + tid] = rsqrtf(1.0f + (float)cnt[tid]);  // +1 self-loop
        }
    }
    __syncthreads();
    for (int j = s + tid; j < e; j += 256) {
        unsigned int p = pair[j];
        int pos = atomicAdd(&cur[p >> PACK_SHIFT], 1);
        csr_col[pos] = (int)(p & PACK_MASK);
    }
}

// ---------------------------------------------------------------------------
// GEMM1 (split-K x4, line-batched): grid (196, 4).  Block = 512 rows x one
// 128-wide K-chunk; 2 rows/thread.  Inner loop loads a FULL 128B line (8x
// float4) per row-stream into registers before computing, so each line is
// fetched once and fully consumed immediately (R8 fix) -- and the 16
// independent loads per group give the MLP that R7 lacked.
// ---------------------------------------------------------------------------
__global__ __launch_bounds__(256) void k_gemm1(
        const float* __restrict__ x, const float* __restrict__ W1,
        float* __restrict__ p0, float* __restrict__ p1,
        float* __restrict__ p2, float* __restrict__ p3, int n) {
    __shared__ float w1s[128 * 16];   // 8KB: this chunk's quarter of W1
    int tid = threadIdx.x;
    int ck = blockIdx.y;
    int k0 = ck << 7;                 // 0,128,256,384
    for (int i = tid; i < 512; i += 256)
        ((float4*)w1s)[i] = ((const float4*)(W1 + (size_t)k0 * 16))[i];
    __syncthreads();

    int base = blockIdx.x * 512 + tid;
    int r0 = base, r1 = base + 256;
    bool l0 = r0 < n, l1 = r1 < n;
    const float4* x0 = (const float4*)(x + (size_t)(l0 ? r0 : 0) * 512 + k0);
    const float4* x1 = (const float4*)(x + (size_t)(l1 ? r1 : 0) * 512 + k0);

    float4 a0[4], a1[4];
    #pragma unroll
    for (int j = 0; j < 4; ++j) {
        a0[j] = make_float4(0.f, 0.f, 0.f, 0.f);
        a1[j] = make_float4(0.f, 0.f, 0.f, 0.f);
    }

    for (int g = 0; g < 4; ++g) {          // 4 groups of 8 quads (=128B line)
        float4 xv0[8], xv1[8];
        #pragma unroll
        for (int t = 0; t < 8; ++t) {      // batch: full line per stream
            xv0[t] = x0[g * 8 + t];
            xv1[t] = x1[g * 8 + t];
        }
        #pragma unroll
        for (int t = 0; t < 8; ++t) {
            const float4* w = (const float4*)(w1s + (g * 8 + t) * 64);
            #pragma unroll
            for (int j = 0; j < 4; ++j) {
                float4 w0 = w[4 * j + 0], w1 = w[4 * j + 1],
                       w2 = w[4 * j + 2], w3 = w[4 * j + 3];
                float k0v = (j == 0) ? xv0[t].x : (j == 1) ? xv0[t].y
                          : (j == 2) ? xv0[t].z : xv0[t].w;
                float k1v = (j == 0) ? xv1[t].x : (j == 1) ? xv1[t].y
                          : (j == 2) ? xv1[t].z : xv1[t].w;
                a0[0].x += k0v * w0.x; a0[0].y += k0v * w0.y;
                a0[0].z += k0v * w0.z; a0[0].w += k0v * w0.w;
                a0[1].x += k0v * w1.x; a0[1].y += k0v * w1.y;
                a0[1].z += k0v * w1.z; a0[1].w += k0v * w1.w;
                a0[2].x += k0v * w2.x; a0[2].y += k0v * w2.y;
                a0[2].z += k0v * w2.z; a0[2].w += k0v * w2.w;
                a0[3].x += k0v * w3.x; a0[3].y += k0v * w3.y;
                a0[3].z += k0v * w3.z; a0[3].w += k0v * w3.w;
                a1[0].x += k1v * w0.x; a1[0].y += k1v * w0.y;
                a1[0].z += k1v * w0.z; a1[0].w += k1v * w0.w;
                a1[1].x += k1v * w1.x; a1[1].y += k1v * w1.y;
                a1[1].z += k1v * w1.z; a1[1].w += k1v * w1.w;
                a1[2].x += k1v * w2.x; a1[2].y += k1v * w2.y;
                a1[2].z += k1v * w2.z; a1[2].w += k1v * w2.w;
                a1[3].x += k1v * w3.x; a1[3].y += k1v * w3.y;
                a1[3].z += k1v * w3.z; a1[3].w += k1v * w3.w;
            }
        }
    }
    float* dst = (ck == 0) ? p0 : (ck == 1) ? p1 : (ck == 2) ? p2 : p3;
    if (l0) {
        float4* o = (float4*)(dst + (size_t)r0 * 16);
        #pragma unroll
        for (int j = 0; j < 4; ++j) o[j] = a0[j];
    }
    if (l1) {
        float4* o = (float4*)(dst + (size_t)r1 * 16);
        #pragma unroll
        for (int j = 0; j < 4; ++j) o[j] = a1[j];
    }
}

// ---------------------------------------------------------------------------
// Reduce split-K partials + apply dinv: hn = (p0+p1+p2+p3) * dinv.
// NOTE: hn aliases p3 -- each thread reads index i from all four partials
// into registers BEFORE storing hn[i] (in-thread order; indices disjoint
// across threads), so the alias is safe.
// ---------------------------------------------------------------------------
__global__ __launch_bounds__(256) void k_hred(
        const float4* __restrict__ p0, const float4* __restrict__ p1,
        const float4* __restrict__ p2, const float4* __restrict__ p3,
        const float* __restrict__ dinv, float4* __restrict__ hn, int n4) {
    int i = blockIdx.x * 256 + threadIdx.x;
    if (i >= n4) return;
    float d = dinv[i >> 2];
    float4 a = p0[i], b = p1[i], c = p2[i], e = p3[i];
    hn[i] = make_float4((a.x + b.x + c.x + e.x) * d, (a.y + b.y + c.y + e.y) * d,
                        (a.z + b.z + c.z + e.z) * d, (a.w + b.w + c.w + e.w) * d);
}

// ---------------------------------------------------------------------------
// Layer-1 aggregation + fused relu/b1/dinv: wave per node.
// Lane layout: slot = lane>>2 (16 edge slots), q = lane&3 (float4 of row).
// u[i] = relu(dinv[i]*(hn[i]+sum hn[col]) + b1) * dinv[i]
// ---------------------------------------------------------------------------
__global__ __launch_bounds__(256) void k_agg1(
        const float* __restrict__ hn, const int* __restrict__ row_ptr,
        const int* __restrict__ csr_col, const float* __restrict__ dinv,
        const float* __restrict__ b1, float* __restrict__ u, int n) {
    int wid = threadIdx.x >> 6, lane = threadIdx.x & 63;
    int i = blockIdx.x * 4 + wid;
    if (i >= n) return;
    int slot = lane >> 2, q = lane & 3;
    int start = row_ptr[i], end = row_ptr[i + 1];

    float4 acc = {0.f, 0.f, 0.f, 0.f};
    int j = start + slot;
    int c = (j < end) ? csr_col[j] : 0;
    while (j < end) {
        int jn = j + 16;
        int cn = (jn < end) ? csr_col[jn] : 0;   // prefetch next col
        float4 v = *(const float4*)(hn + (size_t)c * 16 + 4 * q);
        acc.x += v.x; acc.y += v.y; acc.z += v.z; acc.w += v.w;
        c = cn; j = jn;
    }
    #pragma unroll
    for (int off = 4; off < 64; off <<= 1) {
        acc.x += __shfl_xor(acc.x, off);
        acc.y += __shfl_xor(acc.y, off);
        acc.z += __shfl_xor(acc.z, off);
        acc.w += __shfl_xor(acc.w, off);
    }
    float d = dinv[i];
    float4 hs = *(const float4*)(hn + (size_t)i * 16 + 4 * q);
    float4 bb = *(const float4*)(b1 + 4 * q);
    float4 uo;
    uo.x = fmaxf((acc.x + hs.x) * d + bb.x, 0.f) * d;
    uo.y = fmaxf((acc.y + hs.y) * d + bb.y, 0.f) * d;
    uo.z = fmaxf((acc.z + hs.z) * d + bb.z, 0.f) * d;
    uo.w = fmaxf((acc.w + hs.w) * d + bb.w, 0.f) * d;
    if (lane < 4) *(float4*)(u + (size_t)i * 16 + 4 * q) = uo;  // 64B store
}

// ---------------------------------------------------------------------------
// Layer-2 aggregation (16-wide) + fused W2 GEMM + b2 + log_softmax.
// ---------------------------------------------------------------------------
__global__ __launch_bounds__(256) void k_agg2f(
        const float* __restrict__ u, const int* __restrict__ row_ptr,
        const int* __restrict__ csr_col, const float* __restrict__ dinv,
        const float* __restrict__ W2, const float* __restrict__ b2,
        float* __restrict__ out, int n) {
    __shared__ float w2s[640];
    int tid = threadIdx.x;
    if (tid < 160) ((float4*)w2s)[tid] = ((const float4*)W2)[tid];
    __syncthreads();

    int wid = tid >> 6, lane = tid & 63;
    int i = blockIdx.x * 4 + wid;
    if (i >= n) return;
    int slot = lane >> 2, q = lane & 3;
    int start = row_ptr[i], end = row_ptr[i + 1];

    float4 acc = {0.f, 0.f, 0.f, 0.f};
    int j = start + slot;
    int c = (j < end) ? csr_col[j] : 0;
    while (j < end) {
        int jn = j + 16;
        int cn = (jn < end) ? csr_col[jn] : 0;
        float4 v = *(const float4*)(u + (size_t)c * 16 + 4 * q);
        acc.x += v.x; acc.y += v.y; acc.z += v.z; acc.w += v.w;
        c = cn; j = jn;
    }
    #pragma unroll
    for (int off = 4; off < 64; off <<= 1) {
        acc.x += __shfl_xor(acc.x, off);
        acc.y += __shfl_xor(acc.y, off);
        acc.z += __shfl_xor(acc.z, off);
        acc.w += __shfl_xor(acc.w, off);
    }
    float d = dinv[i];
    float4 us = *(const float4*)(u + (size_t)i * 16 + 4 * q);
    float4 s4;
    s4.x = (acc.x + us.x) * d;
    s4.y = (acc.y + us.y) * d;
    s4.z = (acc.z + us.z) * d;
    s4.w = (acc.w + us.w) * d;

    // GEMM 16x40: lane j (<40) accumulates out[j]; broadcast s from lanes 0..3
    bool act = lane < 40;
    float o = 0.f;
    #pragma unroll
    for (int q2 = 0; q2 < 4; ++q2) {
        float sx = __shfl(s4.x, q2);
        float sy = __shfl(s4.y, q2);
        float sz = __shfl(s4.z, q2);
        float sw = __shfl(s4.w, q2);
        if (act) {
            o += sx * w2s[(4 * q2 + 0) * 40 + lane];
            o += sy * w2s[(4 * q2 + 1) * 40 + lane];
            o += sz * w2s[(4 * q2 + 2) * 40 + lane];
            o += sw * w2s[(4 * q2 + 3) * 40 + lane];
        }
    }
    float v = act ? (o + b2[lane]) : -INFINITY;
    float m = v;
    #pragma unroll
    for (int off = 1; off < 64; off <<= 1) m = fmaxf(m, __shfl_xor(m, off));
    float ex = act ? __expf(v - m) : 0.f;
    float s = ex;
    #pragma unroll
    for (int off = 1; off < 64; off <<= 1) s += __shfl_xor(s, off);
    float ls = __logf(s) + m;
    if (act) out[(size_t)i * 40 + lane] = v - ls;
}

extern "C" void kernel_launch(void* const* d_in, const int* in_sizes, int n_in,
                              void* d_out, int out_size, void* d_ws, size_t ws_size,
                              hipStream_t stream) {
    const float* x  = (const float*)d_in[0];
    const void*  ei = d_in[1];
    const float* W1 = (const float*)d_in[2];
    const float* b1 = (const float*)d_in[3];
    const float* W2 = (const float*)d_in[4];
    const float* b2 = (const float*)d_in[5];
    float* out = (float*)d_out;

    const int n = in_sizes[0] / 512;
    const int E = in_sizes[1] / 2;
    const int nbuck = (n + 127) >> BSHIFT;   // 128 rows/bucket (<=1024 buckets)

    // workspace layout (256B aligned blocks)
    char* w = (char*)d_ws;
    size_t off = 0;
    auto take = [&](size_t bytes) { void* p = w + off; off = (off + bytes + 255) & ~(size_t)255; return p; };
    int*   flag    = (int*)take(4);
    float* dinv    = (float*)take((size_t)n * 4);
    int*   row_ptr = (int*)take((size_t)(n + 1) * 4);
    int*   bcnt    = (int*)take(4096);
    int*   bbase   = (int*)take(4100);
    int*   bcur    = (int*)take(4096);
    float* hn      = (float*)take((size_t)n * 16 * 4);
    float* u       = (float*)take((size_t)n * 16 * 4);
    int*   csr_col = (int*)take((size_t)E * 4);
    // union region: pair (E u32, dead after k_bsort2) then partials p0,p1.
    size_t union_bytes = (size_t)E * 4;
    size_t two_parts   = (size_t)n * 32 * 4;
    if (two_parts > union_bytes) union_bytes = two_parts;
    char* un = (char*)take(union_bytes);
    unsigned int* pair = (unsigned int*)un;
    float* part0 = (float*)un;
    float* part1 = part0 + (size_t)n * 16;
    float* part2 = u;    // u is not written until k_agg1 (after k_hred)
    float* part3 = hn;   // in-place reduce in k_hred (read-before-write per thread)
    (void)ws_size;

    const int nb4  = (n + 3) / 4;
    const int nbB  = (E + CHUNK_E - 1) / CHUNK_E;
    const int nbG  = (n + 511) / 512;
    const int n4   = n * 4;

    k_detect   <<<1, 64, 0, stream>>>((const int*)ei, flag);
    k_zero     <<<(nbuck + 255) / 256, 256, 0, stream>>>(bcnt, nbuck);
    k_bhist    <<<nbB, 256, 0, stream>>>(ei, flag, bcnt, E, nbuck);
    k_bscan    <<<1, 1024, 0, stream>>>(bcnt, bbase, bcur, nbuck, E, row_ptr, n);
    k_bscatter <<<nbB, 256, 0, stream>>>(ei, flag, bcur, pair, E, nbuck);
    k_bsort2   <<<nbuck, 256, 0, stream>>>(pair, bbase, row_ptr, dinv, csr_col, n);
    k_gemm1    <<<dim3(nbG, 4), 256, 0, stream>>>(x, W1, part0, part1, part2, part3, n);
    k_hred     <<<(n4 + 255) / 256, 256, 0, stream>>>((const float4*)part0,
                   (const float4*)part1, (const float4*)part2, (const float4*)part3,
                   dinv, (float4*)hn, n4);
    k_agg1     <<<nb4, 256, 0, stream>>>(hn, row_ptr, csr_col, dinv, b1, u, n);
    k_agg2f    <<<nb4, 256, 0, stream>>>(u, row_ptr, csr_col, dinv, W2, b2, out, n);
}

// Round 10
// 315.020 us; speedup vs baseline: 1.5518x; 1.5518x over previous
//
#include <hip/hip_runtime.h>
#include <math.h>

// ---------------------------------------------------------------------------
// GCN forward, CSR + 16-wide aggregation for BOTH layers.
// Algebra #1: norm = dinv[r]*dinv[c] => pre-scale features by dinv[c],
//   post-scale row sums by dinv[r].
// Algebra #2: W2 is linear => aggregate the 16-wide u = relu(.)*dinv and
//   apply W2 AFTER aggregation (64B/edge gather over a 6.4MB table).
// CSR build (hierarchical; R3/R4 lesson: no large random atomic targets):
//   k_bhist -> k_bscan -> k_bscatter -> k_bsort2, packed 32-bit pairs.
// GEMM1 history: R5 per-lane row streams = L2-amplification floor (~8x line
//   re-reads, ~50-100us); R8/R9 pushed occupancy -> L1/L2 thrash, FETCH 3-4x
//   logical. R10 fix: COALESCED LDS STAGING -- stage 16-float K-chunks into a
//   transposed xs[kq][row] tile (16KB; stage 64B-contiguous per 4 lanes, each
//   line fetched ONCE), compute reads consecutive float4s (optimal banking).
//   W1 read via wave-uniform global addresses (scalar/broadcast path, ~1KB
//   hot per chunk) -- not staged, so 16KB LDS -> 8 blocks/CU and inter-block
//   overlap hides stage latency. Full K per block -> no split-K, no k_hred.
// ---------------------------------------------------------------------------

#define BSHIFT 7          // 128 rows per bucket
#define CHUNK_E 8192      // edges per bucketing block
#define PACK_SHIFT 25
#define PACK_MASK 0x01FFFFFF

__global__ void k_detect(const int* __restrict__ ei32, int* __restrict__ flag) {
    int t = threadIdx.x;
    bool z = (ei32[2 * t + 1] == 0);
    unsigned long long m = __ballot(z);
    if (t == 0) *flag = (m == 0xFFFFFFFFFFFFFFFFULL) ? 1 : 0;
}

__global__ void k_zero(int* __restrict__ p, int n) {
    int i = blockIdx.x * blockDim.x + threadIdx.x;
    if (i < n) p[i] = 0;
}

// ---------------------------------------------------------------------------
// Pass A: per-block LDS histogram of row-buckets; <=nbuck global atomics/block.
// ---------------------------------------------------------------------------
__global__ __launch_bounds__(256) void k_bhist(
        const void* __restrict__ ei, const int* __restrict__ flag,
        int* __restrict__ bcnt, int E, int nbuck) {
    __shared__ int cnt[1024];
    int tid = threadIdx.x;
    for (int i = tid; i < nbuck; i += 256) cnt[i] = 0;
    __syncthreads();
    int e0 = blockIdx.x * CHUNK_E;
    int e1 = min(E, e0 + CHUNK_E);
    bool f = (*flag) != 0;
    for (int e = e0 + tid; e < e1; e += 256) {
        int r = f ? (int)((const long long*)ei)[e] : ((const int*)ei)[e];
        atomicAdd(&cnt[r >> BSHIFT], 1);
    }
    __syncthreads();
    for (int i = tid; i < nbuck; i += 256)
        if (cnt[i]) atomicAdd(&bcnt[i], cnt[i]);
}

// ---------------------------------------------------------------------------
// Scan bucket counts -> bbase (exclusive), bcur (working copy).
// ---------------------------------------------------------------------------
__global__ __launch_bounds__(1024) void k_bscan(
        const int* __restrict__ bcnt, int* __restrict__ bbase,
        int* __restrict__ bcur, int nbuck, int E,
        int* __restrict__ row_ptr, int n) {
    __shared__ int ls[1024];
    int t = threadIdx.x;
    int v = (t < nbuck) ? bcnt[t] : 0;
    ls[t] = v; __syncthreads();
    for (int off = 1; off < 1024; off <<= 1) {
        int tmp = (t >= off) ? ls[t - off] : 0;
        __syncthreads();
        ls[t] += tmp;
        __syncthreads();
    }
    int ex = ls[t] - v;  // exclusive
    if (t < nbuck) { bbase[t] = ex; bcur[t] = ex; }
    if (t == 0) { bbase[nbuck] = E; row_ptr[n] = E; }
}

// ---------------------------------------------------------------------------
// Pass B: bucket edges into contiguous per-bucket segments (packed 32-bit).
// ---------------------------------------------------------------------------
__global__ __launch_bounds__(256) void k_bscatter(
        const void* __restrict__ ei, const int* __restrict__ flag,
        int* __restrict__ bcur, unsigned int* __restrict__ pair, int E, int nbuck) {
    __shared__ int cnt[1024];
    __shared__ int runs[1024];
    int tid = threadIdx.x;
    for (int i = tid; i < nbuck; i += 256) cnt[i] = 0;
    __syncthreads();
    int e0 = blockIdx.x * CHUNK_E;
    int e1 = min(E, e0 + CHUNK_E);
    bool f = (*flag) != 0;
    for (int e = e0 + tid; e < e1; e += 256) {
        int r = f ? (int)((const long long*)ei)[e] : ((const int*)ei)[e];
        atomicAdd(&cnt[r >> BSHIFT], 1);
    }
    __syncthreads();
    for (int i = tid; i < nbuck; i += 256) {
        int c = cnt[i];
        runs[i] = (c > 0) ? atomicAdd(&bcur[i], c) : 0;
        cnt[i] = 0;  // reuse as local cursor
    }
    __syncthreads();
    for (int e = e0 + tid; e < e1; e += 256) {
        int r, c;
        if (f) { const long long* p = (const long long*)ei; r = (int)p[e]; c = (int)p[E + e]; }
        else   { const int* p = (const int*)ei;             r = p[e];      c = p[E + e]; }
        int b = r >> BSHIFT;
        int pos = runs[b] + atomicAdd(&cnt[b], 1);
        pair[pos] = ((unsigned int)(r & 127) << PACK_SHIFT) | (unsigned int)c;
    }
}

// ---------------------------------------------------------------------------
// Pass C: one block per bucket. LDS histogram -> local exclusive scan ->
// row_ptr + dinv (fused rsqrt), then LDS-cursor scatter to csr_col.
// ---------------------------------------------------------------------------
__global__ __launch_bounds__(256) void k_bsort2(
        const unsigned int* __restrict__ pair, const int* __restrict__ bbase,
        int* __restrict__ row_ptr, float* __restrict__ dinv,
        int* __restrict__ csr_col, int n) {
    __shared__ int cnt[128];
    __shared__ int scn[128];
    __shared__ int cur[128];
    int b = blockIdx.x;
    int lo = b << BSHIFT, hi = min(n, lo + 128);
    int nr = hi - lo;
    int tid = threadIdx.x;
    if (tid < 128) cnt[tid] = 0;
    __syncthreads();
    int s = bbase[b], e = bbase[b + 1];
    for (int j = s + tid; j < e; j += 256)
        atomicAdd(&cnt[pair[j] >> PACK_SHIFT], 1);
    __syncthreads();
    if (tid < 128) scn[tid] = cnt[tid];
    __syncthreads();
    for (int off = 1; off < 128; off <<= 1) {
        int tval = (tid < 128 && tid >= off) ? scn[tid - off] : 0;
        __syncthreads();
        if (tid < 128) scn[tid] += tval;
        __syncthreads();
    }
    if (tid < 128) {
        int rp = s + scn[tid] - cnt[tid];  // exclusive
        cur[tid] = rp;
        if (tid < nr) {
            row_ptr[lo + tid] = rp;
            dinv[lo + tid] = rsqrtf(1.0f + (float)cnt[tid]);  // +1 self-loop
        }
    }
    __syncthreads();
    for (int j = s + tid; j < e; j += 256) {
        unsigned int p = pair[j];
        int pos = atomicAdd(&cur[p >> PACK_SHIFT], 1);
        csr_col[pos] = (int)(p & PACK_MASK);
    }
}

// ---------------------------------------------------------------------------
// GEMM1 (LDS-staged, full K): 256 rows/block (391 blocks), 1 row/thread.
// Per 16-float K-chunk: stage into TRANSPOSED xs[kq][row] (stage: 4 lanes x
// 64B contiguous per row, 16 rows/instr -- every line fetched once; writes
// hit 8 lanes per bank-position = optimal; compute reads xs[kq][tid] =
// consecutive float4s = optimal). W1 rows read with wave-uniform global
// addresses (broadcast/scalar path). 16KB LDS -> 8 blocks/CU; inter-block
// overlap hides the stage/sync phases. hn written directly with dinv scale.
// ---------------------------------------------------------------------------
__global__ __launch_bounds__(256) void k_gemm1(
        const float* __restrict__ x, const float* __restrict__ W1,
        const float* __restrict__ dinv, float* __restrict__ hn, int n) {
    __shared__ float4 xs[4][256];     // [kq][row], 16KB
    const int tid = threadIdx.x;
    const int rbase = blockIdx.x * 256;

    float4 a0 = {0,0,0,0}, a1 = {0,0,0,0}, a2 = {0,0,0,0}, a3 = {0,0,0,0};

    for (int c = 0; c < 32; ++c) {
        __syncthreads();              // previous chunk's readers done
        #pragma unroll
        for (int t = 0; t < 4; ++t) {
            int f = t * 256 + tid;
            int row = f >> 2, kq = f & 3;
            int gr = rbase + row;
            float4 v = make_float4(0.f, 0.f, 0.f, 0.f);
            if (gr < n)
                v = *(const float4*)(x + (size_t)gr * 512 + c * 16 + kq * 4);
            xs[kq][row] = v;
        }
        __syncthreads();
        #pragma unroll
        for (int kq = 0; kq < 4; ++kq) {
            float4 xv = xs[kq][tid];
            const float4* wr = (const float4*)(W1 + ((size_t)c * 16 + kq * 4) * 16);
            #pragma unroll
            for (int jj = 0; jj < 4; ++jj) {
                float xk = (jj == 0) ? xv.x : (jj == 1) ? xv.y
                         : (jj == 2) ? xv.z : xv.w;
                float4 w0 = wr[jj * 4 + 0], w1 = wr[jj * 4 + 1],
                       w2 = wr[jj * 4 + 2], w3 = wr[jj * 4 + 3];
                a0.x += xk * w0.x; a0.y += xk * w0.y;
                a0.z += xk * w0.z; a0.w += xk * w0.w;
                a1.x += xk * w1.x; a1.y += xk * w1.y;
                a1.z += xk * w1.z; a1.w += xk * w1.w;
                a2.x += xk * w2.x; a2.y += xk * w2.y;
                a2.z += xk * w2.z; a2.w += xk * w2.w;
                a3.x += xk * w3.x; a3.y += xk * w3.y;
                a3.z += xk * w3.z; a3.w += xk * w3.w;
            }
        }
    }
    int row = rbase + tid;
    if (row < n) {
        float d = dinv[row];
        float4* o = (float4*)(hn + (size_t)row * 16);
        o[0] = make_float4(a0.x * d, a0.y * d, a0.z * d, a0.w * d);
        o[1] = make_float4(a1.x * d, a1.y * d, a1.z * d, a1.w * d);
        o[2] = make_float4(a2.x * d, a2.y * d, a2.z * d, a2.w * d);
        o[3] = make_float4(a3.x * d, a3.y * d, a3.z * d, a3.w * d);
    }
}

// ---------------------------------------------------------------------------
// Layer-1 aggregation + fused relu/b1/dinv: wave per node.
// Lane layout: slot = lane>>2 (16 edge slots), q = lane&3 (float4 of row).
// u[i] = relu(dinv[i]*(hn[i]+sum hn[col]) + b1) * dinv[i]
// ---------------------------------------------------------------------------
__global__ __launch_bounds__(256) void k_agg1(
        const float* __restrict__ hn, const int* __restrict__ row_ptr,
        const int* __restrict__ csr_col, const float* __restrict__ dinv,
        const float* __restrict__ b1, float* __restrict__ u, int n) {
    int wid = threadIdx.x >> 6, lane = threadIdx.x & 63;
    int i = blockIdx.x * 4 + wid;
    if (i >= n) return;
    int slot = lane >> 2, q = lane & 3;
    int start = row_ptr[i], end = row_ptr[i + 1];

    float4 acc = {0.f, 0.f, 0.f, 0.f};
    int j = start + slot;
    int c = (j < end) ? csr_col[j] : 0;
    while (j < end) {
        int jn = j + 16;
        int cn = (jn < end) ? csr_col[jn] : 0;   // prefetch next col
        float4 v = *(const float4*)(hn + (size_t)c * 16 + 4 * q);
        acc.x += v.x; acc.y += v.y; acc.z += v.z; acc.w += v.w;
        c = cn; j = jn;
    }
    #pragma unroll
    for (int off = 4; off < 64; off <<= 1) {
        acc.x += __shfl_xor(acc.x, off);
        acc.y += __shfl_xor(acc.y, off);
        acc.z += __shfl_xor(acc.z, off);
        acc.w += __shfl_xor(acc.w, off);
    }
    float d = dinv[i];
    float4 hs = *(const float4*)(hn + (size_t)i * 16 + 4 * q);
    float4 bb = *(const float4*)(b1 + 4 * q);
    float4 uo;
    uo.x = fmaxf((acc.x + hs.x) * d + bb.x, 0.f) * d;
    uo.y = fmaxf((acc.y + hs.y) * d + bb.y, 0.f) * d;
    uo.z = fmaxf((acc.z + hs.z) * d + bb.z, 0.f) * d;
    uo.w = fmaxf((acc.w + hs.w) * d + bb.w, 0.f) * d;
    if (lane < 4) *(float4*)(u + (size_t)i * 16 + 4 * q) = uo;  // 64B store
}

// ---------------------------------------------------------------------------
// Layer-2 aggregation (16-wide) + fused W2 GEMM + b2 + log_softmax.
// ---------------------------------------------------------------------------
__global__ __launch_bounds__(256) void k_agg2f(
        const float* __restrict__ u, const int* __restrict__ row_ptr,
        const int* __restrict__ csr_col, const float* __restrict__ dinv,
        const float* __restrict__ W2, const float* __restrict__ b2,
        float* __restrict__ out, int n) {
    __shared__ float w2s[640];
    int tid = threadIdx.x;
    if (tid < 160) ((float4*)w2s)[tid] = ((const float4*)W2)[tid];
    __syncthreads();

    int wid = tid >> 6, lane = tid & 63;
    int i = blockIdx.x * 4 + wid;
    if (i >= n) return;
    int slot = lane >> 2, q = lane & 3;
    int start = row_ptr[i], end = row_ptr[i + 1];

    float4 acc = {0.f, 0.f, 0.f, 0.f};
    int j = start + slot;
    int c = (j < end) ? csr_col[j] : 0;
    while (j < end) {
        int jn = j + 16;
        int cn = (jn < end) ? csr_col[jn] : 0;
        float4 v = *(const float4*)(u + (size_t)c * 16 + 4 * q);
        acc.x += v.x; acc.y += v.y; acc.z += v.z; acc.w += v.w;
        c = cn; j = jn;
    }
    #pragma unroll
    for (int off = 4; off < 64; off <<= 1) {
        acc.x += __shfl_xor(acc.x, off);
        acc.y += __shfl_xor(acc.y, off);
        acc.z += __shfl_xor(acc.z, off);
        acc.w += __shfl_xor(acc.w, off);
    }
    float d = dinv[i];
    float4 us = *(const float4*)(u + (size_t)i * 16 + 4 * q);
    float4 s4;
    s4.x = (acc.x + us.x) * d;
    s4.y = (acc.y + us.y) * d;
    s4.z = (acc.z + us.z) * d;
    s4.w = (acc.w + us.w) * d;

    // GEMM 16x40: lane j (<40) accumulates out[j]; broadcast s from lanes 0..3
    bool act = lane < 40;
    float o = 0.f;
    #pragma unroll
    for (int q2 = 0; q2 < 4; ++q2) {
        float sx = __shfl(s4.x, q2);
        float sy = __shfl(s4.y, q2);
        float sz = __shfl(s4.z, q2);
        float sw = __shfl(s4.w, q2);
        if (act) {
            o += sx * w2s[(4 * q2 + 0) * 40 + lane];
            o += sy * w2s[(4 * q2 + 1) * 40 + lane];
            o += sz * w2s[(4 * q2 + 2) * 40 + lane];
            o += sw * w2s[(4 * q2 + 3) * 40 + lane];
        }
    }
    float v = act ? (o + b2[lane]) : -INFINITY;
    float m = v;
    #pragma unroll
    for (int off = 1; off < 64; off <<= 1) m = fmaxf(m, __shfl_xor(m, off));
    float ex = act ? __expf(v - m) : 0.f;
    float s = ex;
    #pragma unroll
    for (int off = 1; off < 64; off <<= 1) s += __shfl_xor(s, off);
    float ls = __logf(s) + m;
    if (act) out[(size_t)i * 40 + lane] = v - ls;
}

extern "C" void kernel_launch(void* const* d_in, const int* in_sizes, int n_in,
                              void* d_out, int out_size, void* d_ws, size_t ws_size,
                              hipStream_t stream) {
    const float* x  = (const float*)d_in[0];
    const void*  ei = d_in[1];
    const float* W1 = (const float*)d_in[2];
    const float* b1 = (const float*)d_in[3];
    const float* W2 = (const float*)d_in[4];
    const float* b2 = (const float*)d_in[5];
    float* out = (float*)d_out;

    const int n = in_sizes[0] / 512;
    const int E = in_sizes[1] / 2;
    const int nbuck = (n + 127) >> BSHIFT;   // 128 rows/bucket (<=1024 buckets)

    // workspace layout (256B aligned blocks)
    char* w = (char*)d_ws;
    size_t off = 0;
    auto take = [&](size_t bytes) { void* p = w + off; off = (off + bytes + 255) & ~(size_t)255; return p; };
    int*   flag    = (int*)take(4);
    float* dinv    = (float*)take((size_t)n * 4);
    int*   row_ptr = (int*)take((size_t)(n + 1) * 4);
    int*   bcnt    = (int*)take(4096);
    int*   bbase   = (int*)take(4100);
    int*   bcur    = (int*)take(4096);
    float* hn      = (float*)take((size_t)n * 16 * 4);
    float* u       = (float*)take((size_t)n * 16 * 4);
    int*   csr_col = (int*)take((size_t)E * 4);
    unsigned int* pair = (unsigned int*)take((size_t)E * 4);
    (void)ws_size;

    const int nb  = (n + 255) / 256;
    const int nb4 = (n + 3) / 4;
    const int nbB = (E + CHUNK_E - 1) / CHUNK_E;

    k_detect   <<<1, 64, 0, stream>>>((const int*)ei, flag);
    k_zero     <<<(nbuck + 255) / 256, 256, 0, stream>>>(bcnt, nbuck);
    k_bhist    <<<nbB, 256, 0, stream>>>(ei, flag, bcnt, E, nbuck);
    k_bscan    <<<1, 1024, 0, stream>>>(bcnt, bbase, bcur, nbuck, E, row_ptr, n);
    k_bscatter <<<nbB, 256, 0, stream>>>(ei, flag, bcur, pair, E, nbuck);
    k_bsort2   <<<nbuck, 256, 0, stream>>>(pair, bbase, row_ptr, dinv, csr_col, n);
    k_gemm1    <<<nb, 256, 0, stream>>>(x, W1, dinv, hn, n);
    k_agg1     <<<nb4, 256, 0, stream>>>(hn, row_ptr, csr_col, dinv, b1, u, n);
    k_agg2f    <<<nb4, 256, 0, stream>>>(u, row_ptr, csr_col, dinv, W2, b2, out, n);
}

// Round 11
// 284.357 us; speedup vs baseline: 1.7191x; 1.1078x over previous
//
#include <hip/hip_runtime.h>
#include <math.h>

// ---------------------------------------------------------------------------
// GCN forward, CSR + 16-wide aggregation for BOTH layers.
// Algebra #1: norm = dinv[r]*dinv[c] => pre-scale features by dinv[c],
//   post-scale row sums by dinv[r].
// Algebra #2: W2 is linear => aggregate the 16-wide u = relu(.)*dinv and
//   apply W2 AFTER aggregation (64B/edge gather over a 6.4MB table).
// CSR build (hierarchical; R3/R4 lesson: no large random atomic targets):
//   k_bhist -> k_bscan -> k_bscatter -> k_bsort2, packed 32-bit pairs.
// GEMM1 history: R5-R9 established (a) per-lane row streams cause L1/L2 line
//   re-fetch amplification (FETCH 3-4x logical), (b) LDS staging fixes FETCH
//   but R10's load->write-immediately pattern serialized ~900cyc HBM latency
//   per chunk at 1.5 blocks/CU (140us, all pipes <20%).
// R11: single-wave blocks (64 rows, 1563 blocks, barriers ~free) + REGISTER
//   PREFETCH (next chunk loaded during compute; latency hidden) + 32-float
//   chunks (stage reads = full 128B line per row) + padded LDS xs[8][65]
//   (write banks 4*(kq+row)%32 all distinct -> no conflicts).
// ---------------------------------------------------------------------------

#define BSHIFT 7          // 128 rows per bucket
#define CHUNK_E 8192      // edges per bucketing block
#define PACK_SHIFT 25
#define PACK_MASK 0x01FFFFFF

__global__ void k_detect(const int* __restrict__ ei32, int* __restrict__ flag) {
    int t = threadIdx.x;
    bool z = (ei32[2 * t + 1] == 0);
    unsigned long long m = __ballot(z);
    if (t == 0) *flag = (m == 0xFFFFFFFFFFFFFFFFULL) ? 1 : 0;
}

__global__ void k_zero(int* __restrict__ p, int n) {
    int i = blockIdx.x * blockDim.x + threadIdx.x;
    if (i < n) p[i] = 0;
}

// ---------------------------------------------------------------------------
// Pass A: per-block LDS histogram of row-buckets; <=nbuck global atomics/block.
// ---------------------------------------------------------------------------
__global__ __launch_bounds__(256) void k_bhist(
        const void* __restrict__ ei, const int* __restrict__ flag,
        int* __restrict__ bcnt, int E, int nbuck) {
    __shared__ int cnt[1024];
    int tid = threadIdx.x;
    for (int i = tid; i < nbuck; i += 256) cnt[i] = 0;
    __syncthreads();
    int e0 = blockIdx.x * CHUNK_E;
    int e1 = min(E, e0 + CHUNK_E);
    bool f = (*flag) != 0;
    for (int e = e0 + tid; e < e1; e += 256) {
        int r = f ? (int)((const long long*)ei)[e] : ((const int*)ei)[e];
        atomicAdd(&cnt[r >> BSHIFT], 1);
    }
    __syncthreads();
    for (int i = tid; i < nbuck; i += 256)
        if (cnt[i]) atomicAdd(&bcnt[i], cnt[i]);
}

// ---------------------------------------------------------------------------
// Scan bucket counts -> bbase (exclusive), bcur (working copy).
// ---------------------------------------------------------------------------
__global__ __launch_bounds__(1024) void k_bscan(
        const int* __restrict__ bcnt, int* __restrict__ bbase,
        int* __restrict__ bcur, int nbuck, int E,
        int* __restrict__ row_ptr, int n) {
    __shared__ int ls[1024];
    int t = threadIdx.x;
    int v = (t < nbuck) ? bcnt[t] : 0;
    ls[t] = v; __syncthreads();
    for (int off = 1; off < 1024; off <<= 1) {
        int tmp = (t >= off) ? ls[t - off] : 0;
        __syncthreads();
        ls[t] += tmp;
        __syncthreads();
    }
    int ex = ls[t] - v;  // exclusive
    if (t < nbuck) { bbase[t] = ex; bcur[t] = ex; }
    if (t == 0) { bbase[nbuck] = E; row_ptr[n] = E; }
}

// ---------------------------------------------------------------------------
// Pass B: bucket edges into contiguous per-bucket segments (packed 32-bit).
// ---------------------------------------------------------------------------
__global__ __launch_bounds__(256) void k_bscatter(
        const void* __restrict__ ei, const int* __restrict__ flag,
        int* __restrict__ bcur, unsigned int* __restrict__ pair, int E, int nbuck) {
    __shared__ int cnt[1024];
    __shared__ int runs[1024];
    int tid = threadIdx.x;
    for (int i = tid; i < nbuck; i += 256) cnt[i] = 0;
    __syncthreads();
    int e0 = blockIdx.x * CHUNK_E;
    int e1 = min(E, e0 + CHUNK_E);
    bool f = (*flag) != 0;
    for (int e = e0 + tid; e < e1; e += 256) {
        int r = f ? (int)((const long long*)ei)[e] : ((const int*)ei)[e];
        atomicAdd(&cnt[r >> BSHIFT], 1);
    }
    __syncthreads();
    for (int i = tid; i < nbuck; i += 256) {
        int c = cnt[i];
        runs[i] = (c > 0) ? atomicAdd(&bcur[i], c) : 0;
        cnt[i] = 0;  // reuse as local cursor
    }
    __syncthreads();
    for (int e = e0 + tid; e < e1; e += 256) {
        int r, c;
        if (f) { const long long* p = (const long long*)ei; r = (int)p[e]; c = (int)p[E + e]; }
        else   { const int* p = (const int*)ei;             r = p[e];      c = p[E + e]; }
        int b = r >> BSHIFT;
        int pos = runs[b] + atomicAdd(&cnt[b], 1);
        pair[pos] = ((unsigned int)(r & 127) << PACK_SHIFT) | (unsigned int)c;
    }
}

// ---------------------------------------------------------------------------
// Pass C: one block per bucket. LDS histogram -> local exclusive scan ->
// row_ptr + dinv (fused rsqrt), then LDS-cursor scatter to csr_col.
// ---------------------------------------------------------------------------
__global__ __launch_bounds__(256) void k_bsort2(
        const unsigned int* __restrict__ pair, const int* __restrict__ bbase,
        int* __restrict__ row_ptr, float* __restrict__ dinv,
        int* __restrict__ csr_col, int n) {
    __shared__ int cnt[128];
    __shared__ int scn[128];
    __shared__ int cur[128];
    int b = blockIdx.x;
    int lo = b << BSHIFT, hi = min(n, lo + 128);
    int nr = hi - lo;
    int tid = threadIdx.x;
    if (tid < 128) cnt[tid] = 0;
    __syncthreads();
    int s = bbase[b], e = bbase[b + 1];
    for (int j = s + tid; j < e; j += 256)
        atomicAdd(&cnt[pair[j] >> PACK_SHIFT], 1);
    __syncthreads();
    if (tid < 128) scn[tid] = cnt[tid];
    __syncthreads();
    for (int off = 1; off < 128; off <<= 1) {
        int tval = (tid < 128 && tid >= off) ? scn[tid - off] : 0;
        __syncthreads();
        if (tid < 128) scn[tid] += tval;
        __syncthreads();
    }
    if (tid < 128) {
        int rp = s + scn[tid] - cnt[tid];  // exclusive
        cur[tid] = rp;
        if (tid < nr) {
            row_ptr[lo + tid] = rp;
            dinv[lo + tid] = rsqrtf(1.0f + (float)cnt[tid]);  // +1 self-loop
        }
    }
    __syncthreads();
    for (int j = s + tid; j < e; j += 256) {
        unsigned int p = pair[j];
        int pos = atomicAdd(&cur[p >> PACK_SHIFT], 1);
        csr_col[pos] = (int)(p & PACK_MASK);
    }
}

// ---------------------------------------------------------------------------
// GEMM1 (single-wave blocks + register prefetch): 64 rows/block, 1563 blocks.
// 16 K-chunks of 32 floats. Stage read: 8 lanes x float4 = one full 128B line
// per row per wave-instr (each line fetched once, consumed immediately).
// Prefetch: chunk c+1 loaded to regs during chunk c's compute -> HBM latency
// hidden. LDS xs[8][65] pad: write banks 4*(kq+row)%32 all distinct.
// W1 read wave-uniform from global (scalar/broadcast path).
// ---------------------------------------------------------------------------
__global__ __launch_bounds__(64) void k_gemm1(
        const float* __restrict__ x, const float* __restrict__ W1,
        const float* __restrict__ dinv, float* __restrict__ hn, int n) {
    __shared__ float4 xs[8][65];      // [kq][row], padded (8.3KB)
    const int tid = threadIdx.x;      // 0..63
    const int rbase = blockIdx.x * 64;
    const int lrow = tid >> 3, lkq = tid & 7;   // stage mapping

    float4 pf[8];
    auto LOAD = [&](int c) {
        #pragma unroll
        for (int t = 0; t < 8; ++t) {
            int gr = rbase + t * 8 + lrow;
            pf[t] = (gr < n)
                  ? *(const float4*)(x + (size_t)gr * 512 + c * 32 + lkq * 4)
                  : make_float4(0.f, 0.f, 0.f, 0.f);
        }
    };
    LOAD(0);

    float4 a0 = {0,0,0,0}, a1 = {0,0,0,0}, a2 = {0,0,0,0}, a3 = {0,0,0,0};

    for (int c = 0; c < 16; ++c) {
        __syncthreads();              // prev compute done reading xs
        #pragma unroll
        for (int t = 0; t < 8; ++t)
            xs[lkq][t * 8 + lrow] = pf[t];
        if (c < 15) LOAD(c + 1);      // issue next chunk; overlaps compute
        __syncthreads();              // writes visible
        #pragma unroll
        for (int kq = 0; kq < 8; ++kq) {
            float4 xv = xs[kq][tid];
            const float4* wr = (const float4*)(W1 + ((size_t)c * 32 + kq * 4) * 16);
            #pragma unroll
            for (int jj = 0; jj < 4; ++jj) {
                float xk = (jj == 0) ? xv.x : (jj == 1) ? xv.y
                         : (jj == 2) ? xv.z : xv.w;
                float4 w0 = wr[jj * 4 + 0], w1 = wr[jj * 4 + 1],
                       w2 = wr[jj * 4 + 2], w3 = wr[jj * 4 + 3];
                a0.x += xk * w0.x; a0.y += xk * w0.y;
                a0.z += xk * w0.z; a0.w += xk * w0.w;
                a1.x += xk * w1.x; a1.y += xk * w1.y;
                a1.z += xk * w1.z; a1.w += xk * w1.w;
                a2.x += xk * w2.x; a2.y += xk * w2.y;
                a2.z += xk * w2.z; a2.w += xk * w2.w;
                a3.x += xk * w3.x; a3.y += xk * w3.y;
                a3.z += xk * w3.z; a3.w += xk * w3.w;
            }
        }
    }
    int row = rbase + tid;
    if (row < n) {
        float d = dinv[row];
        float4* o = (float4*)(hn + (size_t)row * 16);
        o[0] = make_float4(a0.x * d, a0.y * d, a0.z * d, a0.w * d);
        o[1] = make_float4(a1.x * d, a1.y * d, a1.z * d, a1.w * d);
        o[2] = make_float4(a2.x * d, a2.y * d, a2.z * d, a2.w * d);
        o[3] = make_float4(a3.x * d, a3.y * d, a3.z * d, a3.w * d);
    }
}

// ---------------------------------------------------------------------------
// Layer-1 aggregation + fused relu/b1/dinv: wave per node.
// Lane layout: slot = lane>>2 (16 edge slots), q = lane&3 (float4 of row).
// u[i] = relu(dinv[i]*(hn[i]+sum hn[col]) + b1) * dinv[i]
// ---------------------------------------------------------------------------
__global__ __launch_bounds__(256) void k_agg1(
        const float* __restrict__ hn, const int* __restrict__ row_ptr,
        const int* __restrict__ csr_col, const float* __restrict__ dinv,
        const float* __restrict__ b1, float* __restrict__ u, int n) {
    int wid = threadIdx.x >> 6, lane = threadIdx.x & 63;
    int i = blockIdx.x * 4 + wid;
    if (i >= n) return;
    int slot = lane >> 2, q = lane & 3;
    int start = row_ptr[i], end = row_ptr[i + 1];

    float4 acc = {0.f, 0.f, 0.f, 0.f};
    int j = start + slot;
    int c = (j < end) ? csr_col[j] : 0;
    while (j < end) {
        int jn = j + 16;
        int cn = (jn < end) ? csr_col[jn] : 0;   // prefetch next col
        float4 v = *(const float4*)(hn + (size_t)c * 16 + 4 * q);
        acc.x += v.x; acc.y += v.y; acc.z += v.z; acc.w += v.w;
        c = cn; j = jn;
    }
    #pragma unroll
    for (int off = 4; off < 64; off <<= 1) {
        acc.x += __shfl_xor(acc.x, off);
        acc.y += __shfl_xor(acc.y, off);
        acc.z += __shfl_xor(acc.z, off);
        acc.w += __shfl_xor(acc.w, off);
    }
    float d = dinv[i];
    float4 hs = *(const float4*)(hn + (size_t)i * 16 + 4 * q);
    float4 bb = *(const float4*)(b1 + 4 * q);
    float4 uo;
    uo.x = fmaxf((acc.x + hs.x) * d + bb.x, 0.f) * d;
    uo.y = fmaxf((acc.y + hs.y) * d + bb.y, 0.f) * d;
    uo.z = fmaxf((acc.z + hs.z) * d + bb.z, 0.f) * d;
    uo.w = fmaxf((acc.w + hs.w) * d + bb.w, 0.f) * d;
    if (lane < 4) *(float4*)(u + (size_t)i * 16 + 4 * q) = uo;  // 64B store
}

// ---------------------------------------------------------------------------
// Layer-2 aggregation (16-wide) + fused W2 GEMM + b2 + log_softmax.
// ---------------------------------------------------------------------------
__global__ __launch_bounds__(256) void k_agg2f(
        const float* __restrict__ u, const int* __restrict__ row_ptr,
        const int* __restrict__ csr_col, const float* __restrict__ dinv,
        const float* __restrict__ W2, const float* __restrict__ b2,
        float* __restrict__ out, int n) {
    __shared__ float w2s[640];
    int tid = threadIdx.x;
    if (tid < 160) ((float4*)w2s)[tid] = ((const float4*)W2)[tid];
    __syncthreads();

    int wid = tid >> 6, lane = tid & 63;
    int i = blockIdx.x * 4 + wid;
    if (i >= n) return;
    int slot = lane >> 2, q = lane & 3;
    int start = row_ptr[i], end = row_ptr[i + 1];

    float4 acc = {0.f, 0.f, 0.f, 0.f};
    int j = start + slot;
    int c = (j < end) ? csr_col[j] : 0;
    while (j < end) {
        int jn = j + 16;
        int cn = (jn < end) ? csr_col[jn] : 0;
        float4 v = *(const float4*)(u + (size_t)c * 16 + 4 * q);
        acc.x += v.x; acc.y += v.y; acc.z += v.z; acc.w += v.w;
        c = cn; j = jn;
    }
    #pragma unroll
    for (int off = 4; off < 64; off <<= 1) {
        acc.x += __shfl_xor(acc.x, off);
        acc.y += __shfl_xor(acc.y, off);
        acc.z += __shfl_xor(acc.z, off);
        acc.w += __shfl_xor(acc.w, off);
    }
    float d = dinv[i];
    float4 us = *(const float4*)(u + (size_t)i * 16 + 4 * q);
    float4 s4;
    s4.x = (acc.x + us.x) * d;
    s4.y = (acc.y + us.y) * d;
    s4.z = (acc.z + us.z) * d;
    s4.w = (acc.w + us.w) * d;

    // GEMM 16x40: lane j (<40) accumulates out[j]; broadcast s from lanes 0..3
    bool act = lane < 40;
    float o = 0.f;
    #pragma unroll
    for (int q2 = 0; q2 < 4; ++q2) {
        float sx = __shfl(s4.x, q2);
        float sy = __shfl(s4.y, q2);
        float sz = __shfl(s4.z, q2);
        float sw = __shfl(s4.w, q2);
        if (act) {
            o += sx * w2s[(4 * q2 + 0) * 40 + lane];
            o += sy * w2s[(4 * q2 + 1) * 40 + lane];
            o += sz * w2s[(4 * q2 + 2) * 40 + lane];
            o += sw * w2s[(4 * q2 + 3) * 40 + lane];
        }
    }
    float v = act ? (o + b2[lane]) : -INFINITY;
    float m = v;
    #pragma unroll
    for (int off = 1; off < 64; off <<= 1) m = fmaxf(m, __shfl_xor(m, off));
    float ex = act ? __expf(v - m) : 0.f;
    float s = ex;
    #pragma unroll
    for (int off = 1; off < 64; off <<= 1) s += __shfl_xor(s, off);
    float ls = __logf(s) + m;
    if (act) out[(size_t)i * 40 + lane] = v - ls;
}

extern "C" void kernel_launch(void* const* d_in, const int* in_sizes, int n_in,
                              void* d_out, int out_size, void* d_ws, size_t ws_size,
                              hipStream_t stream) {
    const float* x  = (const float*)d_in[0];
    const void*  ei = d_in[1];
    const float* W1 = (const float*)d_in[2];
    const float* b1 = (const float*)d_in[3];
    const float* W2 = (const float*)d_in[4];
    const float* b2 = (const float*)d_in[5];
    float* out = (float*)d_out;

    const int n = in_sizes[0] / 512;
    const int E = in_sizes[1] / 2;
    const int nbuck = (n + 127) >> BSHIFT;   // 128 rows/bucket (<=1024 buckets)

    // workspace layout (256B aligned blocks)
    char* w = (char*)d_ws;
    size_t off = 0;
    auto take = [&](size_t bytes) { void* p = w + off; off = (off + bytes + 255) & ~(size_t)255; return p; };
    int*   flag    = (int*)take(4);
    float* dinv    = (float*)take((size_t)n * 4);
    int*   row_ptr = (int*)take((size_t)(n + 1) * 4);
    int*   bcnt    = (int*)take(4096);
    int*   bbase   = (int*)take(4100);
    int*   bcur    = (int*)take(4096);
    float* hn      = (float*)take((size_t)n * 16 * 4);
    float* u       = (float*)take((size_t)n * 16 * 4);
    int*   csr_col = (int*)take((size_t)E * 4);
    unsigned int* pair = (unsigned int*)take((size_t)E * 4);
    (void)ws_size;

    const int nb4 = (n + 3) / 4;
    const int nbB = (E + CHUNK_E - 1) / CHUNK_E;
    const int nbG = (n + 63) / 64;

    k_detect   <<<1, 64, 0, stream>>>((const int*)ei, flag);
    k_zero     <<<(nbuck + 255) / 256, 256, 0, stream>>>(bcnt, nbuck);
    k_bhist    <<<nbB, 256, 0, stream>>>(ei, flag, bcnt, E, nbuck);
    k_bscan    <<<1, 1024, 0, stream>>>(bcnt, bbase, bcur, nbuck, E, row_ptr, n);
    k_bscatter <<<nbB, 256, 0, stream>>>(ei, flag, bcur, pair, E, nbuck);
    k_bsort2   <<<nbuck, 256, 0, stream>>>(pair, bbase, row_ptr, dinv, csr_col, n);
    k_gemm1    <<<nbG, 64, 0, stream>>>(x, W1, dinv, hn, n);
    k_agg1     <<<nb4, 256, 0, stream>>>(hn, row_ptr, csr_col, dinv, b1, u, n);
    k_agg2f    <<<nb4, 256, 0, stream>>>(u, row_ptr, csr_col, dinv, W2, b2, out, n);
}